// Round 20
// baseline (1601.824 us; speedup 1.0000x reference)
//
#include <hip/hip_runtime.h>

// GNODecoder round 20: r19's scalar-pipe B worked (1130 us, SGPR 112, 0
// conflicts) but s_load batches miss sL1 (concurrent set 5blk x 4wave x
// 12KB >> 16KB) -> ~200cyc L2 latency per batch, ~16-32 FMAs of work per
// batch = 25% duty. Fix: 2 EDGES PER LANE -- same 16-weight batch now
// feeds 32 FMAs, halving the latency-exposed term per FLOP. M=128 tile
// (lane owns rows m and m+64), L2 as two 16-col passes (C[2][16]=32 regs,
// peak ~60 = the measured grant; chunk-fission harmless: s_loads re-hit,
// A re-reads are own-row b128). LDS 47.2 KB -> 3 blocks/CU = 12 waves
// (occupancy non-binding past ~12, r12). Sort/proj/QB=24 = r19 proven.

#define BLOCK 256

#define OFF_HT   0      // [128][68] m-major, 8704 floats
#define OFF_SACC 8704   // [QB*129]

__device__ __forceinline__ float gelu_f(float x) {
    // jax.nn.gelu default (approximate=True, tanh form)
    float x3 = x * x * x;
    float t  = 0.7978845608028654f * fmaf(0.044715f, x3, x);
    float e  = __expf(2.0f * t);
    float r  = __builtin_amdgcn_rcpf(e + 1.0f);
    return 0.5f * x * (1.0f + (1.0f - 2.0f * r));
}

// ---------- sort machinery (proven) ----------

__global__ void hist_kernel(const int* __restrict__ dst, int* __restrict__ hist, int E) {
    int e = blockIdx.x * blockDim.x + threadIdx.x;
    if (e < E) atomicAdd(&hist[dst[e]], 1);
}

__global__ __launch_bounds__(1024) void scan_kernel(const int* __restrict__ hist,
                                                    int* __restrict__ start, int n) {
    __shared__ int wsum[16];
    __shared__ int woff[16];
    int tid = threadIdx.x;
    int lane = tid & 63, wid = tid >> 6;
    int carry = 0;  // meaningful on tid 0 only
    for (int base = 0; base < n; base += 1024) {
        int i = base + tid;
        int v = (i < n) ? hist[i] : 0;
        int incl = v;
#pragma unroll
        for (int off = 1; off < 64; off <<= 1) {
            int t = __shfl_up(incl, off, 64);
            if (lane >= off) incl += t;
        }
        if (lane == 63) wsum[wid] = incl;
        __syncthreads();
        if (tid == 0) {
            int acc = carry;
#pragma unroll
            for (int w = 0; w < 16; ++w) { woff[w] = acc; acc += wsum[w]; }
            carry = acc;
        }
        __syncthreads();
        if (i < n) start[i] = woff[wid] + incl - v;
        __syncthreads();
    }
    if (threadIdx.x == 0) start[n] = carry;
}

__global__ void scatter_kernel(const int* __restrict__ dst, const int* __restrict__ src,
                               const int* __restrict__ start, int* __restrict__ cursor,
                               int* __restrict__ dsts, int* __restrict__ srcs, int E) {
    int e = blockIdx.x * blockDim.x + threadIdx.x;
    if (e >= E) return;
    int d = dst[e];
    int pos = start[d] + atomicAdd(&cursor[d], 1);
    dsts[pos] = d;
    srcs[pos] = src[e];
}

// ---------- fused: 2 edges/lane, wave-per-n-slice, B via scalar pipe ----------

template <int QB, bool FUSED_PROJ>
__global__ __launch_bounds__(BLOCK) void fused_kernel(
    const float* __restrict__ rndata,   // [NL,128]
    const float* __restrict__ qpos,     // [NQ,3]
    const float* __restrict__ lpos,     // [NL,3]
    const int*   __restrict__ dsts,     // [E] sorted by dst
    const int*   __restrict__ srcs,     // [E]
    const int*   __restrict__ start,    // [NQ+1]
    const float* __restrict__ W0, const float* __restrict__ b0,
    const float* __restrict__ W1, const float* __restrict__ b1,
    const float* __restrict__ W2, const float* __restrict__ b2,
    const float* __restrict__ P0, const float* __restrict__ pb0,
    const float* __restrict__ P1, const float* __restrict__ pb1,
    float* __restrict__ agg,            // [NQ,128] mean (path A)
    float* __restrict__ out,            // [NQ,4]   (FUSED_PROJ)
    int nq)
{
    extern __shared__ float smem[];
    const int tid = threadIdx.x;
    float* hT   = smem + OFF_HT;    // [128][68] row = edge, cols = h channels
    float* sacc = smem + OFF_SACC;  // [QB][129]

    for (int i = tid; i < QB * 129; i += BLOCK) sacc[i] = 0.f;

    const int q0   = blockIdx.x * QB;
    const int qend = min(q0 + QB, nq);
    const int e0 = start[q0], e1 = start[qend];
    const int ntiles = (e1 - e0 + 127) >> 7;

    const int m   = tid & 63;                                         // row A; row B = m+64
    const int wn1 = __builtin_amdgcn_readfirstlane((tid >> 6) * 16);  // L0/L1 n-slice
    const int wp2 = __builtin_amdgcn_readfirstlane((tid >> 6) * 32);  // L2 n-base (2 passes)

    for (int t = 0; t < ntiles; ++t) {
        const int ebase = e0 + (t << 7);
        int  eA = ebase + m,       eB = ebase + 64 + m;
        bool vA = eA < e1,         vB = eB < e1;
        int  dA = vA ? dsts[eA] : q0,  sA = vA ? srcs[eA] : 0;
        int  dB = vB ? dsts[eB] : q0,  sB = vB ? srcs[eB] : 0;
        float pA[6], pB[6];
        {
            const float* p = qpos + dA * 3; pA[0] = p[0]; pA[1] = p[1]; pA[2] = p[2];
            p = lpos + sA * 3;              pA[3] = p[0]; pA[4] = p[1]; pA[5] = p[2];
            p = qpos + dB * 3;              pB[0] = p[0]; pB[1] = p[1]; pB[2] = p[2];
            p = lpos + sB * 3;              pB[3] = p[0]; pB[4] = p[1]; pB[5] = p[2];
        }

        // ---- L0: cols [wn1,wn1+16), both edges; B = W0 via s_load ----
        float C0A[16], C0B[16];
#pragma unroll
        for (int j = 0; j < 16; ++j) { C0A[j] = b0[wn1 + j]; C0B[j] = C0A[j]; }
#pragma unroll
        for (int k = 0; k < 6; ++k) {
            float aA = pA[k], aB = pB[k];
#pragma unroll
            for (int j = 0; j < 16; ++j) {
                float wv = W0[k * 64 + wn1 + j];
                C0A[j] = fmaf(aA, wv, C0A[j]);
                C0B[j] = fmaf(aB, wv, C0B[j]);
            }
        }
        __syncthreads();  // prev tile's L2 hT reads done (t==0: sacc init)
#pragma unroll
        for (int j4 = 0; j4 < 4; ++j4) {
            float4 oA = make_float4(gelu_f(C0A[4 * j4 + 0]), gelu_f(C0A[4 * j4 + 1]),
                                    gelu_f(C0A[4 * j4 + 2]), gelu_f(C0A[4 * j4 + 3]));
            float4 oB = make_float4(gelu_f(C0B[4 * j4 + 0]), gelu_f(C0B[4 * j4 + 1]),
                                    gelu_f(C0B[4 * j4 + 2]), gelu_f(C0B[4 * j4 + 3]));
            *(float4*)(hT + m * 68 + wn1 + 4 * j4) = oA;
            *(float4*)(hT + (64 + m) * 68 + wn1 + 4 * j4) = oB;
        }
        __syncthreads();  // h0 ready

        // ---- L1: cols [wn1,wn1+16) over k=0..63; A = own rows; B = W1 s_load ----
        float C1A[16], C1B[16];
#pragma unroll
        for (int j = 0; j < 16; ++j) { C1A[j] = b1[wn1 + j]; C1B[j] = C1A[j]; }
#pragma unroll 2
        for (int k4 = 0; k4 < 16; ++k4) {
            float4 a4A = *(const float4*)(hT + m * 68 + k4 * 4);
            float4 a4B = *(const float4*)(hT + (64 + m) * 68 + k4 * 4);
            float avA[4] = {a4A.x, a4A.y, a4A.z, a4A.w};
            float avB[4] = {a4B.x, a4B.y, a4B.z, a4B.w};
#pragma unroll
            for (int kk = 0; kk < 4; ++kk) {
                float aA = avA[kk], aB = avB[kk];
#pragma unroll
                for (int j = 0; j < 16; ++j) {
                    float wv = W1[(k4 * 4 + kk) * 64 + wn1 + j];
                    C1A[j] = fmaf(aA, wv, C1A[j]);
                    C1B[j] = fmaf(aB, wv, C1B[j]);
                }
            }
        }
        __syncthreads();  // all h0 reads done
#pragma unroll
        for (int j4 = 0; j4 < 4; ++j4) {
            float4 oA = make_float4(gelu_f(C1A[4 * j4 + 0]), gelu_f(C1A[4 * j4 + 1]),
                                    gelu_f(C1A[4 * j4 + 2]), gelu_f(C1A[4 * j4 + 3]));
            float4 oB = make_float4(gelu_f(C1B[4 * j4 + 0]), gelu_f(C1B[4 * j4 + 1]),
                                    gelu_f(C1B[4 * j4 + 2]), gelu_f(C1B[4 * j4 + 3]));
            *(float4*)(hT + m * 68 + wn1 + 4 * j4) = oA;
            *(float4*)(hT + (64 + m) * 68 + wn1 + 4 * j4) = oB;
        }
        __syncthreads();  // h1 ready

        // ---- L2: two 16-col passes at [wp2+p*16); B = W2 s_load ----
#pragma unroll 1
        for (int p = 0; p < 2; ++p) {
            const int nc = wp2 + p * 16;
            float C2A[16], C2B[16];
#pragma unroll
            for (int j = 0; j < 16; ++j) { C2A[j] = b2[nc + j]; C2B[j] = C2A[j]; }
#pragma unroll 2
            for (int k4 = 0; k4 < 16; ++k4) {
                float4 a4A = *(const float4*)(hT + m * 68 + k4 * 4);
                float4 a4B = *(const float4*)(hT + (64 + m) * 68 + k4 * 4);
                float avA[4] = {a4A.x, a4A.y, a4A.z, a4A.w};
                float avB[4] = {a4B.x, a4B.y, a4B.z, a4B.w};
#pragma unroll
                for (int kk = 0; kk < 4; ++kk) {
                    float aA = avA[kk], aB = avB[kk];
#pragma unroll
                    for (int j = 0; j < 16; ++j) {
                        float wv = W2[(k4 * 4 + kk) * 128 + nc + j];
                        C2A[j] = fmaf(aA, wv, C2A[j]);
                        C2B[j] = fmaf(aB, wv, C2B[j]);
                    }
                }
            }
            if (vA) {
                const float* r  = rndata + (size_t)sA * 128 + nc;
                float*       ac = &sacc[(dA - q0) * 129 + nc];
#pragma unroll
                for (int j4 = 0; j4 < 4; ++j4) {
                    float4 rv = *(const float4*)(r + 4 * j4);
                    atomicAdd(&ac[4 * j4 + 0], C2A[4 * j4 + 0] * rv.x);
                    atomicAdd(&ac[4 * j4 + 1], C2A[4 * j4 + 1] * rv.y);
                    atomicAdd(&ac[4 * j4 + 2], C2A[4 * j4 + 2] * rv.z);
                    atomicAdd(&ac[4 * j4 + 3], C2A[4 * j4 + 3] * rv.w);
                }
            }
            if (vB) {
                const float* r  = rndata + (size_t)sB * 128 + nc;
                float*       ac = &sacc[(dB - q0) * 129 + nc];
#pragma unroll
                for (int j4 = 0; j4 < 4; ++j4) {
                    float4 rv = *(const float4*)(r + 4 * j4);
                    atomicAdd(&ac[4 * j4 + 0], C2B[4 * j4 + 0] * rv.x);
                    atomicAdd(&ac[4 * j4 + 1], C2B[4 * j4 + 1] * rv.y);
                    atomicAdd(&ac[4 * j4 + 2], C2B[4 * j4 + 2] * rv.z);
                    atomicAdd(&ac[4 * j4 + 3], C2B[4 * j4 + 3] * rv.w);
                }
            }
        }
        // next iteration's first barrier orders these hT reads / ds_adds
    }
    __syncthreads();  // last tile's ds_adds visible (and ntiles==0 path)

    if (!FUSED_PROJ) {
        // write per-query mean to global agg (coalesced across c)
        for (int idx = tid; idx < QB * 128; idx += BLOCK) {
            int ql = idx >> 7, c = idx & 127;
            int q  = q0 + ql;
            if (q < qend) {
                float deg = (float)(start[q + 1] - start[q]);
                agg[(size_t)q * 128 + c] = sacc[ql * 129 + c] / fmaxf(deg, 1.f);
            }
        }
    } else {
        if (tid < QB) {
            int q = q0 + tid;
            if (q < nq) {
                float deg = (float)(start[q + 1] - start[q]);
                float inv = 1.0f / fmaxf(deg, 1.f);
                const float* aq = &sacc[tid * 129];
                float o0 = pb1[0], o1 = pb1[1], o2 = pb1[2], o3 = pb1[3];
#pragma unroll 1
                for (int jj = 0; jj < 256; jj += 8) {
                    float acc[8];
#pragma unroll
                    for (int u = 0; u < 8; ++u) acc[u] = pb0[jj + u];
#pragma unroll
                    for (int i = 0; i < 128; ++i) {
                        float av = aq[i] * inv;
#pragma unroll
                        for (int u = 0; u < 8; ++u)
                            acc[u] = fmaf(av, P0[i * 256 + jj + u], acc[u]);
                    }
#pragma unroll
                    for (int u = 0; u < 8; ++u) {
                        float h = gelu_f(acc[u]);
                        o0 = fmaf(h, P1[(jj + u) * 4 + 0], o0);
                        o1 = fmaf(h, P1[(jj + u) * 4 + 1], o1);
                        o2 = fmaf(h, P1[(jj + u) * 4 + 2], o2);
                        o3 = fmaf(h, P1[(jj + u) * 4 + 3], o3);
                    }
                }
                float4* o4 = (float4*)(out + (size_t)q * 4);
                *o4 = make_float4(o0, o1, o2, o3);
            }
        }
    }
}

// ---------- projection: plain r7/r9 kernel (proven ~270 us) ----------

__global__ __launch_bounds__(256) void proj_kernel(
    const float* __restrict__ agg,      // [NQ,128] mean
    const float* __restrict__ P0, const float* __restrict__ pb0,
    const float* __restrict__ P1, const float* __restrict__ pb1,
    float* __restrict__ out, int nq)
{
    int q = blockIdx.x * blockDim.x + threadIdx.x;
    if (q >= nq) return;

    float a[128];
    const float4* ag4 = (const float4*)(agg + (size_t)q * 128);
#pragma unroll
    for (int i = 0; i < 32; ++i) {
        float4 v = ag4[i];
        a[4 * i + 0] = v.x; a[4 * i + 1] = v.y;
        a[4 * i + 2] = v.z; a[4 * i + 3] = v.w;
    }

    float o0 = pb1[0], o1 = pb1[1], o2 = pb1[2], o3 = pb1[3];
#pragma unroll 1
    for (int jj = 0; jj < 256; jj += 8) {
        float acc[8];
#pragma unroll
        for (int u = 0; u < 8; ++u) acc[u] = pb0[jj + u];
#pragma unroll
        for (int i = 0; i < 128; ++i) {
            float av = a[i];
#pragma unroll
            for (int u = 0; u < 8; ++u)
                acc[u] = fmaf(av, P0[i * 256 + jj + u], acc[u]);
        }
#pragma unroll
        for (int u = 0; u < 8; ++u) {
            float h = gelu_f(acc[u]);
            o0 = fmaf(h, P1[(jj + u) * 4 + 0], o0);
            o1 = fmaf(h, P1[(jj + u) * 4 + 1], o1);
            o2 = fmaf(h, P1[(jj + u) * 4 + 2], o2);
            o3 = fmaf(h, P1[(jj + u) * 4 + 3], o3);
        }
    }
    float4* o4 = (float4*)(out + (size_t)q * 4);
    *o4 = make_float4(o0, o1, o2, o3);
}

extern "C" void kernel_launch(void* const* d_in, const int* in_sizes, int n_in,
                              void* d_out, int out_size, void* d_ws, size_t ws_size,
                              hipStream_t stream)
{
    const float* rndata = (const float*)d_in[0];
    const float* qpos   = (const float*)d_in[1];
    const float* lpos   = (const float*)d_in[2];
    const int*   dst    = (const int*)d_in[3];
    const int*   src    = (const int*)d_in[4];
    const float* W0  = (const float*)d_in[5];
    const float* b0  = (const float*)d_in[6];
    const float* W1  = (const float*)d_in[7];
    const float* b1  = (const float*)d_in[8];
    const float* W2  = (const float*)d_in[9];
    const float* b2  = (const float*)d_in[10];
    const float* P0  = (const float*)d_in[11];
    const float* pb0 = (const float*)d_in[12];
    const float* P1  = (const float*)d_in[13];
    const float* pb1 = (const float*)d_in[14];

    int nq = in_sizes[1] / 3;
    int E  = in_sizes[3];

    // ws layout: [agg nq*128 (path A)] [hist] [cursor] [start] [dsts] [srcs]
    size_t agg_bytes  = (size_t)nq * 128 * sizeof(float);
    size_t sort_bytes = 0;
    {
        size_t o = 0;
        o += ((size_t)nq * sizeof(int) + 15) & ~(size_t)15;
        o += ((size_t)nq * sizeof(int) + 15) & ~(size_t)15;
        o += ((size_t)(nq + 1) * sizeof(int) + 15) & ~(size_t)15;
        o += ((size_t)E * sizeof(int) + 15) & ~(size_t)15;
        o += ((size_t)E * sizeof(int) + 15) & ~(size_t)15;
        sort_bytes = o;
    }
    bool path_a = (agg_bytes + sort_bytes) <= ws_size;

    size_t off = path_a ? agg_bytes : 0;
    auto alloc = [&](size_t bytes) {
        void* p = (char*)d_ws + off;
        off += (bytes + 15) & ~(size_t)15;
        return p;
    };
    float* agg   = (float*)d_ws;  // path A only
    int* hist    = (int*)alloc((size_t)nq * sizeof(int));
    int* cursor  = (int*)alloc((size_t)nq * sizeof(int));
    int* start   = (int*)alloc((size_t)(nq + 1) * sizeof(int));
    int* dsts    = (int*)alloc((size_t)E * sizeof(int));
    int* srcs    = (int*)alloc((size_t)E * sizeof(int));

    size_t histpad = ((size_t)nq * sizeof(int) + 15) & ~(size_t)15;
    hipMemsetAsync(hist, 0, 2 * histpad, stream);

    hist_kernel<<<(E + 255) / 256, 256, 0, stream>>>(dst, hist, E);
    scan_kernel<<<1, 1024, 0, stream>>>(hist, start, nq);
    scatter_kernel<<<(E + 255) / 256, 256, 0, stream>>>(dst, src, start, cursor, dsts, srcs, E);

    constexpr int    QB   = 24;
    constexpr size_t SMEM = (size_t)(8704 + QB * 129) * 4;  // 47,200 B -> 3 blocks/CU
    int nb = (nq + QB - 1) / QB;

    if (path_a) {
        fused_kernel<QB, false><<<nb, BLOCK, SMEM, stream>>>(
            rndata, qpos, lpos, dsts, srcs, start,
            W0, b0, W1, b1, W2, b2, P0, pb0, P1, pb1, agg, nullptr, nq);
        proj_kernel<<<(nq + 255) / 256, 256, 0, stream>>>(
            agg, P0, pb0, P1, pb1, (float*)d_out, nq);
    } else {
        fused_kernel<QB, true><<<nb, BLOCK, SMEM, stream>>>(
            rndata, qpos, lpos, dsts, srcs, start,
            W0, b0, W1, b1, W2, b2, P0, pb0, P1, pb1, nullptr, (float*)d_out, nq);
    }
}